// Round 1
// baseline (1067.726 us; speedup 1.0000x reference)
//
#include <hip/hip_runtime.h>
#include <math.h>

#define S 64
#define HF 128
#define WF 128
#define CCH 256
#define NBOX_TOT 128   // 4 batches * 32 boxes
#define PLANE (HF*WF)  // 16384
#define CROP_ELEMS ((size_t)NBOX_TOT * CCH * S * S)  // 134217728

// Per-box affine coefficients, replicated per thread (cheap, once per thread).
__device__ __forceinline__ void box_coeffs(const float* __restrict__ obb, int bn,
                                           float& cx, float& cy, float& wf, float& hf,
                                           float& cs, float& sn) {
    const float* o = obb + bn * 5;
    cx = o[0] * 0.125f;                       // /FEAT_DOWN
    cy = o[1] * 0.125f;
    wf = fmaxf(o[2], 1.0f) * 1.25f * 0.125f;  // *EXPAND/FEAT_DOWN
    hf = fmaxf(o[3], 1.0f) * 1.25f * 0.125f;
    float ang = o[4] * 0.017453292519943295f; // deg2rad
    cs = cosf(ang);
    sn = sinf(ang);
}

// Main kernel: grid = 128 boxes * 16 row-tiles; block = 256 threads.
// Thread -> one output pixel (i,j); loops over all 256 channels.
__global__ __launch_bounds__(256) void roi_crop_kernel(const float* __restrict__ feat,
                                                       const float* __restrict__ obb,
                                                       float* __restrict__ out) {
    const int blk = blockIdx.x;
    const int bn = blk >> 4;        // box index 0..127
    const int tile = blk & 15;      // 16 tiles of 4 rows each
    const int tid = threadIdx.x;
    const int j = tid & 63;
    const int i = tile * 4 + (tid >> 6);
    const int b = bn >> 5;          // batch = bn / 32

    float cx, cy, wf, hf, cs, sn;
    box_coeffs(obb, bn, cx, cy, wf, hf, cs, sn);

    const float sx = wf * (2.0f / WF);
    const float sy = hf * (2.0f / HF);
    const float tx = cx * (2.0f / WF) - 1.0f;
    const float ty = cy * (2.0f / HF) - 1.0f;
    const float a11 = cs * sx, a12 = -sn * sy, a13 = tx;
    const float a21 = sn * sx, a22 = cs * sy, a23 = ty;

    const float X = 2.0f * ((float)j + 0.5f) / (float)S - 1.0f;
    const float Y = 2.0f * ((float)i + 0.5f) / (float)S - 1.0f;
    const float gx = a11 * X + a12 * Y + a13;
    const float gy = a21 * X + a22 * Y + a23;
    const float ix = ((gx + 1.0f) * (float)WF - 1.0f) * 0.5f;
    const float iy = ((gy + 1.0f) * (float)HF - 1.0f) * 0.5f;

    const float x0f = floorf(ix);
    const float y0f = floorf(iy);
    const float wx = ix - x0f;
    const float wy = iy - y0f;
    const int x0 = (int)x0f, y0 = (int)y0f;
    const int x1 = x0 + 1,  y1 = y0 + 1;

    const bool vx0 = (x0 >= 0) & (x0 < WF);
    const bool vx1 = (x1 >= 0) & (x1 < WF);
    const bool vy0 = (y0 >= 0) & (y0 < HF);
    const bool vy1 = (y1 >= 0) & (y1 < HF);

    const int x0c = min(max(x0, 0), WF - 1);
    const int x1c = min(max(x1, 0), WF - 1);
    const int y0c = min(max(y0, 0), HF - 1);
    const int y1c = min(max(y1, 0), HF - 1);

    // Fold validity into weights (matches reference clip+mask exactly).
    const float w00 = (1.0f - wx) * (1.0f - wy) * (float)(vx0 && vy0);
    const float w01 = wx * (1.0f - wy)          * (float)(vx1 && vy0);
    const float w10 = (1.0f - wx) * wy          * (float)(vx0 && vy1);
    const float w11 = wx * wy                   * (float)(vx1 && vy1);

    const int o00 = y0c * WF + x0c;
    const int o01 = y0c * WF + x1c;
    const int o10 = y1c * WF + x0c;
    const int o11 = y1c * WF + x1c;

    const float* __restrict__ p = feat + (size_t)b * CCH * PLANE;
    float* __restrict__ op = out + (size_t)bn * CCH * (S * S) + (size_t)(i * S + j);

#pragma unroll 4
    for (int c = 0; c < CCH; ++c) {
        const float* __restrict__ pc = p + (size_t)c * PLANE;
        float v = w00 * pc[o00] + w01 * pc[o01] + w10 * pc[o10] + w11 * pc[o11];
        // Output is a 537MB stream with no reuse -> nontemporal, keep feat in L2/L3.
        __builtin_nontemporal_store(v, op + (size_t)c * (S * S));
    }
}

// Tiny kernel: the 128 x 2 x 3 affine matrices.
__global__ void roi_mat_kernel(const float* __restrict__ obb, float* __restrict__ outm) {
    const int bn = threadIdx.x;
    if (bn >= NBOX_TOT) return;
    float cx, cy, wf, hf, cs, sn;
    box_coeffs(obb, bn, cx, cy, wf, hf, cs, sn);
    const float A  = cs * (wf / (float)S);
    const float Bv = -sn * (hf / (float)S);
    const float A2 = sn * (wf / (float)S);
    const float B2 = cs * (hf / (float)S);
    const float Cx = cx - 0.5f * (float)S * (A + Bv);
    const float Cy = cy - 0.5f * (float)S * (A2 + B2);
    float* m = outm + bn * 6;
    m[0] = A;  m[1] = Bv; m[2] = Cx;
    m[3] = A2; m[4] = B2; m[5] = Cy;
}

extern "C" void kernel_launch(void* const* d_in, const int* in_sizes, int n_in,
                              void* d_out, int out_size, void* d_ws, size_t ws_size,
                              hipStream_t stream) {
    const float* feat = (const float*)d_in[0];
    const float* obb  = (const float*)d_in[1];
    float* out = (float*)d_out;

    // crops: 128 boxes * 16 tiles blocks, 256 threads (one 64x4 pixel strip each)
    roi_crop_kernel<<<NBOX_TOT * 16, 256, 0, stream>>>(feat, obb, out);
    // M_all appended after crops
    roi_mat_kernel<<<1, NBOX_TOT, 0, stream>>>(obb, out + CROP_ELEMS);
}